// Round 9
// baseline (145.164 us; speedup 1.0000x reference)
//
#include <hip/hip_runtime.h>
#include <hip/hip_bf16.h>
#include <math.h>

#define MDIM 128
#define CDIM 64
#define NKEYS 21844   // sum 4^i, i=1..7
// layer key offsets: c1=0 c2=4 c3=20 c4=84 c5=340 c6=1364 c7=5460

typedef __attribute__((ext_vector_type(8))) __bf16 bf16x8;
typedef __attribute__((ext_vector_type(4))) float f32x4;

// ---------------------------------------------------------------------------
// K0: convert Wk (7x128x128 f32) -> bf16 once.
// ---------------------------------------------------------------------------
__global__ __launch_bounds__(256) void k_cvtw(const float* __restrict__ Wk,
                                              __hip_bfloat16* __restrict__ wkb) {
  const int i = blockIdx.x * 256 + threadIdx.x;   // one float4 per thread
  float4 v = *reinterpret_cast<const float4*>(Wk + (size_t)i * 4);
  __hip_bfloat16 h[4];
  h[0] = __float2bfloat16(v.x); h[1] = __float2bfloat16(v.y);
  h[2] = __float2bfloat16(v.z); h[3] = __float2bfloat16(v.w);
  unsigned long long bits;
  __builtin_memcpy(&bits, h, 8);
  *reinterpret_cast<unsigned long long*>(wkb + (size_t)i * 4) = bits;
}

// ---------------------------------------------------------------------------
// K1: keys via MFMA. One wave per 16 keys (one depth): D = Wk[d] * states^T.
// ---------------------------------------------------------------------------
__global__ __launch_bounds__(64) void k_keys_mfma(const float* __restrict__ states,
                                                  const __hip_bfloat16* __restrict__ wkb,
                                                  const float* __restrict__ bk,
                                                  __hip_bfloat16* __restrict__ keys) {
  const int lane = threadIdx.x;
  const int c = lane & 15, hi = lane >> 4;
  int blk = blockIdx.x, d, t;
  if      (blk < 2)   { d = blk; t = 0; }
  else if (blk < 6)   { d = 2; t = blk - 2; }
  else if (blk < 22)  { d = 3; t = blk - 6; }
  else if (blk < 86)  { d = 4; t = blk - 22; }
  else if (blk < 342) { d = 5; t = blk - 86; }
  else                { d = 6; t = blk - 342; }
  const int cumArr[7] = {0, 4, 20, 84, 340, 1364, 5460};
  const int k0 = cumArr[d] + 16 * t;

  bf16x8 sb[4];
  const float* srow = states + (size_t)(k0 + c) * MDIM;
#pragma unroll
  for (int kf = 0; kf < 4; ++kf) {
    float4 a = *reinterpret_cast<const float4*>(srow + kf * 32 + hi * 8);
    float4 b = *reinterpret_cast<const float4*>(srow + kf * 32 + hi * 8 + 4);
    bf16x8 v;
    v[0] = (__bf16)a.x; v[1] = (__bf16)a.y; v[2] = (__bf16)a.z; v[3] = (__bf16)a.w;
    v[4] = (__bf16)b.x; v[5] = (__bf16)b.y; v[6] = (__bf16)b.z; v[7] = (__bf16)b.w;
    sb[kf] = v;
  }

  const __hip_bfloat16* wkd = wkb + (size_t)d * MDIM * MDIM;
  const float* bkd = bk + d * MDIM;
  const bool valid = (d > 0) || (c < 4);

#pragma unroll
  for (int ct = 0; ct < 8; ++ct) {
    bf16x8 aw[4];
    const __hip_bfloat16* wrow = wkd + (size_t)(ct * 16 + c) * MDIM;
#pragma unroll
    for (int kf = 0; kf < 4; ++kf)
      aw[kf] = *reinterpret_cast<const bf16x8*>(wrow + kf * 32 + hi * 8);
    f32x4 acc = {};
#pragma unroll
    for (int kf = 0; kf < 4; ++kf)
      acc = __builtin_amdgcn_mfma_f32_16x16x32_bf16(aw[kf], sb[kf], acc, 0, 0, 0);
    float4 bias = *reinterpret_cast<const float4*>(bkd + ct * 16 + hi * 4);
    __hip_bfloat16 hv[4];
    hv[0] = __float2bfloat16(fmaxf(acc[0] + bias.x, 0.f));
    hv[1] = __float2bfloat16(fmaxf(acc[1] + bias.y, 0.f));
    hv[2] = __float2bfloat16(fmaxf(acc[2] + bias.z, 0.f));
    hv[3] = __float2bfloat16(fmaxf(acc[3] + bias.w, 0.f));
    if (valid) {
      unsigned long long bits;
      __builtin_memcpy(&bits, hv, 8);
      *reinterpret_cast<unsigned long long*>(
          keys + (size_t)(k0 + c) * MDIM + ct * 16 + 4 * hi) = bits;
    }
  }
}

// ---------------------------------------------------------------------------
// K2: query[b][m] = bq[m] + dot(hidden[b][:64], Wq[m][:64])  -> bf16
// ---------------------------------------------------------------------------
__global__ __launch_bounds__(128) void k_query(const float* __restrict__ hidden,
                                               const float* __restrict__ Wq,
                                               const float* __restrict__ bq,
                                               __hip_bfloat16* __restrict__ query) {
  __shared__ __align__(16) float sH[4][CDIM];
  const int b0 = blockIdx.x * 4;
  const int m  = threadIdx.x;
  for (int idx = m; idx < 4 * CDIM; idx += 128)
    sH[idx >> 6][idx & 63] = hidden[(size_t)b0 * CDIM + idx];
  __syncthreads();
  const float4* wrow = (const float4*)(Wq + (size_t)m * CDIM);
  float acc0 = 0.f, acc1 = 0.f, acc2 = 0.f, acc3 = 0.f;
#pragma unroll
  for (int kq = 0; kq < CDIM / 4; ++kq) {
    float4 w = wrow[kq];
    float4 a = *(const float4*)&sH[0][kq * 4];
    float4 b = *(const float4*)&sH[1][kq * 4];
    float4 c = *(const float4*)&sH[2][kq * 4];
    float4 e = *(const float4*)&sH[3][kq * 4];
    acc0 += w.x * a.x + w.y * a.y + w.z * a.z + w.w * a.w;
    acc1 += w.x * b.x + w.y * b.y + w.z * b.z + w.w * b.w;
    acc2 += w.x * c.x + w.y * c.y + w.z * c.z + w.w * c.w;
    acc3 += w.x * e.x + w.y * e.y + w.z * e.z + w.w * e.w;
  }
  const float bias = bq[m];
  query[(size_t)(b0 + 0) * MDIM + m] = __float2bfloat16(acc0 + bias);
  query[(size_t)(b0 + 1) * MDIM + m] = __float2bfloat16(acc1 + bias);
  query[(size_t)(b0 + 2) * MDIM + m] = __float2bfloat16(acc2 + bias);
  query[(size_t)(b0 + 3) * MDIM + m] = __float2bfloat16(acc3 + bias);
}

// ---------------------------------------------------------------------------
// K3: subtree walker, v9 — r8 structure at 2x occupancy (16 waves/CU).
// Block = 4 waves x 64 b x 4 consecutive depth-5 subtrees. Wave = 16 b.
// Keys staged block-shared (dbuf, swizzled, 1 barrier/tile). Cum chain in
// regs (shuffle parent gather). d7 via per-wave LDS buffer of ONE d6-group
// (16 b x 64 keys, stride 68 — bank-verified in r6), flushed per u5 as
// 4 instrs x 16 rows x 256B contiguous runs. LDS = 25.4KB/block;
// __launch_bounds__(256,4) caps VGPR<=128 -> 4 blocks/CU = 16 waves/CU.
// ---------------------------------------------------------------------------
#define D7STR 68   // padded row stride (floats)

__device__ __forceinline__ float gather_par(const f32x4 cp, int u, int lane) {
  const int src = u * 16 + (lane & 15);
  const float g0 = __shfl(cp[0], src, 64);
  const float g1 = __shfl(cp[1], src, 64);
  const float g2 = __shfl(cp[2], src, 64);
  const float g3 = __shfl(cp[3], src, 64);
  const int hi = lane >> 4;
  const float p01 = (hi & 1) ? g1 : g0;
  const float p23 = (hi & 1) ? g3 : g2;
  return (hi & 2) ? p23 : p01;
}

__device__ __forceinline__ void tile_step(
    const char* __restrict__ gsrc, char* __restrict__ sdst0,
    const char* __restrict__ sKB, int& sbuf, int nextBase,
    const bf16x8 (&qf)[4], const f32x4* cumPrev, int u, f32x4& cumOut,
    float* __restrict__ oPtr, size_t span, bool doStore, bool d1mask,
    float* __restrict__ d7dst, int lane) {
  const int c = lane & 15, hi = lane >> 4;

  // stage next key tile into regs (1 float4/thread; hides under compute)
  float4 stg;
  if (nextBase >= 0)
    stg = *reinterpret_cast<const float4*>(gsrc + (size_t)nextBase * 256);

  // A-frags from swizzled shared LDS tile
  bf16x8 af[4];
#pragma unroll
  for (int kf = 0; kf < 4; ++kf)
    af[kf] = *reinterpret_cast<const bf16x8*>(
        sKB + sbuf * 4096 + c * 256 + (((kf * 4 + hi) ^ (c & 7)) << 4));

  f32x4 acc = {};
  acc = __builtin_amdgcn_mfma_f32_16x16x32_bf16(af[0], qf[0], acc, 0, 0, 0);
  acc = __builtin_amdgcn_mfma_f32_16x16x32_bf16(af[1], qf[1], acc, 0, 0, 0);
  acc = __builtin_amdgcn_mfma_f32_16x16x32_bf16(af[2], qf[2], acc, 0, 0, 0);
  acc = __builtin_amdgcn_mfma_f32_16x16x32_bf16(af[3], qf[3], acc, 0, 0, 0);

  const float mx  = fmaxf(fmaxf(acc[0], acc[1]), fmaxf(acc[2], acc[3]));
  const float lse = mx + __logf(__expf(acc[0] - mx) + __expf(acc[1] - mx) +
                                __expf(acc[2] - mx) + __expf(acc[3] - mx));
  float par = 0.f;
  if (cumPrev) par = gather_par(*cumPrev, u, lane);
  f32x4 cm;
  cm[0] = acc[0] - lse + par;
  cm[1] = acc[1] - lse + par;
  cm[2] = acc[2] - lse + par;
  cm[3] = acc[3] - lse + par;
  cumOut = cm;

  if (d7dst) {
    // row = b (=c), col = u6*16 + hi*4 (stride 68; 2-way max -> free)
    *reinterpret_cast<f32x4*>(d7dst + c * D7STR) = cm;
  } else if (doStore && (!d1mask || hi == 0)) {
    float4 o;
    o.x = cm[0]; o.y = cm[1]; o.z = cm[2]; o.w = cm[3];
    *reinterpret_cast<float4*>(oPtr + (size_t)c * span + hi * 4) = o;
  }

  if (nextBase >= 0)
    *reinterpret_cast<float4*>(sdst0 + (sbuf ^ 1) * 4096) = stg;
  __syncthreads();
  sbuf ^= 1;
}

__global__ __launch_bounds__(256, 4) void k_tree(const __hip_bfloat16* __restrict__ keys,
                                                 const __hip_bfloat16* __restrict__ query,
                                                 float* __restrict__ out, int B) {
  __shared__ __align__(16) float sKeys[2][1024];     // 2 x 4KB shared key tiles
  __shared__ __align__(16) float sD7[4][16 * D7STR]; // per-wave d6-group buffer

  const int tid  = threadIdx.x;
  const int lane = tid & 63;
  const int w    = tid >> 6;
  const int c    = lane & 15, hi = lane >> 4;

  const int chunk = blockIdx.x & 15;     // 4-subtree chunk (XCD = chunk%8)
  const int bg    = blockIdx.x >> 4;     // batch group (64 b per block)
  const int T4    = chunk;
  const int T3    = chunk >> 2;
  const int b0w   = bg * 64 + w * 16;    // wave's 16-b base

  const char* keyBytes = reinterpret_cast<const char*>(keys);
  const int srow = tid >> 4, schunk = tid & 15;
  const char* gsrc = keyBytes + (size_t)srow * 256 + schunk * 16;
  char* sdst0 = reinterpret_cast<char*>(&sKeys[0][0]) + srow * 256 +
                ((schunk ^ (srow & 7)) << 4);
  const char* sKB = reinterpret_cast<const char*>(&sKeys[0][0]);

  // query B-frags (held in regs for all tiles)
  bf16x8 qf[4];
  {
    const __hip_bfloat16* qrow = query + (size_t)(b0w + c) * MDIM;
#pragma unroll
    for (int kf = 0; kf < 4; ++kf)
      qf[kf] = *reinterpret_cast<const bf16x8*>(qrow + kf * 32 + hi * 8);
  }

  // prologue: stage d1 tile (key base 0)
  *reinterpret_cast<float4*>(sdst0) = *reinterpret_cast<const float4*>(gsrc);
  __syncthreads();
  int sbuf = 0;

  f32x4 c1, c2, c3, c4, c5, c6, c7;
  float* d7w = &sD7[w][0];

  // d1 (keys 0..15; quad hi==0 = real d1 nodes)
  tile_step(gsrc, sdst0, sKB, sbuf, 4, qf, nullptr, 0, c1,
            out + (size_t)b0w * 4, 4, chunk == 0, true, nullptr, lane);
  // d2 (keys 4..19)
  tile_step(gsrc, sdst0, sKB, sbuf, 20 + 16 * T3, qf, &c1, 0, c2,
            out + (size_t)4 * B + (size_t)b0w * 16, 16, chunk == 0, false,
            nullptr, lane);
  // d3 (tile T3)
  tile_step(gsrc, sdst0, sKB, sbuf, 84 + 16 * T4, qf, &c2, T3, c3,
            out + (size_t)20 * B + (size_t)b0w * 64 + 16 * T3, 64,
            (chunk & 3) == 0, false, nullptr, lane);
  // d4 (tile T4 = chunk)
  tile_step(gsrc, sdst0, sKB, sbuf, 340 + 16 * (4 * chunk), qf, &c3, chunk & 3, c4,
            out + (size_t)84 * B + (size_t)b0w * 256 + 16 * T4, 256,
            true, false, nullptr, lane);

#pragma unroll 1
  for (int u4 = 0; u4 < 4; ++u4) {
    const int S5 = 4 * chunk + u4;
    // d5 (tile S5); next = first d6 tile
    tile_step(gsrc, sdst0, sKB, sbuf, 1364 + 16 * (4 * S5), qf, &c4, u4, c5,
              out + (size_t)340 * B + (size_t)b0w * 1024 + 16 * S5, 1024,
              true, false, nullptr, lane);
#pragma unroll
    for (int u5 = 0; u5 < 4; ++u5) {
      const int T6 = 4 * S5 + u5;
      // d6 tile T6; next = its first d7 child
      tile_step(gsrc, sdst0, sKB, sbuf, 5460 + 16 * (4 * T6), qf, &c5, u5, c6,
                out + (size_t)1364 * B + (size_t)b0w * 4096 + 16 * T6, 4096,
                true, false, nullptr, lane);
#pragma unroll
      for (int u6 = 0; u6 < 4; ++u6) {
        const int T7 = 4 * T6 + u6;
        int nb;
        if (u6 < 3)      nb = 5460 + 16 * (T7 + 1);
        else if (u5 < 3) nb = 1364 + 16 * (T6 + 1);
        else if (u4 < 3) nb = 340 + 16 * (S5 + 1);
        else             nb = -1;
        tile_step(gsrc, sdst0, sKB, sbuf, nb, qf, &c6, u6, c7,
                  nullptr, 0, false, false, d7w + u6 * 16 + hi * 4, lane);
      }
      // flush d6-group T6's d7: 4 instrs, each 16 rows x 256B contiguous
      {
        float* dst = out + (size_t)5460 * B + (size_t)b0w * 16384 + 64 * T6;
#pragma unroll
        for (int j = 0; j < 4; ++j) {
          const int r = j * 4 + hi;
          f32x4 v = *reinterpret_cast<const f32x4*>(d7w + r * D7STR + c * 4);
          float4 o;
          o.x = v[0]; o.y = v[1]; o.z = v[2]; o.w = v[3];
          *reinterpret_cast<float4*>(dst + (size_t)r * 16384 + c * 4) = o;
        }
      }
    }
  }
}

// ---------------------------------------------------------------------------
extern "C" void kernel_launch(void* const* d_in, const int* in_sizes, int n_in,
                              void* d_out, int out_size, void* d_ws, size_t ws_size,
                              hipStream_t stream) {
  const float* hidden = (const float*)d_in[0];
  const float* Wq     = (const float*)d_in[1];
  const float* bq     = (const float*)d_in[2];
  const float* states = (const float*)d_in[3];
  const float* Wk     = (const float*)d_in[4];
  const float* bk     = (const float*)d_in[5];
  float* out = (float*)d_out;
  const int B = in_sizes[0] / CDIM;  // 4096

  __hip_bfloat16* keys  = (__hip_bfloat16*)d_ws;        // NKEYS*128 bf16
  __hip_bfloat16* query = keys + (size_t)NKEYS * MDIM;  // B*128 bf16
  __hip_bfloat16* wkb   = query + (size_t)B * MDIM;     // 7*128*128 bf16

  k_cvtw<<<(7 * MDIM * MDIM) / (256 * 4), 256, 0, stream>>>(Wk, wkb);
  k_query<<<B / 4, 128, 0, stream>>>(hidden, Wq, bq, query);
  k_keys_mfma<<<1366, 64, 0, stream>>>(states, wkb, bk, keys);

  // grid: chunk-fastest (XCD pinning): 16 chunks x B/64 batch groups
  k_tree<<<(B / 64) * 16, 256, 0, stream>>>(keys, query, out, B);
}

// Round 10
// 130.818 us; speedup vs baseline: 1.1097x; 1.1097x over previous
//
#include <hip/hip_runtime.h>
#include <hip/hip_bf16.h>
#include <math.h>

#define MDIM 128
#define CDIM 64
#define NKEYS 21844   // sum 4^i, i=1..7
// layer key offsets: c1=0 c2=4 c3=20 c4=84 c5=340 c6=1364 c7=5460

typedef __attribute__((ext_vector_type(8))) __bf16 bf16x8;
typedef __attribute__((ext_vector_type(4))) float f32x4;

// ---------------------------------------------------------------------------
// K0: convert Wk (7x128x128 f32) -> bf16 once.
// ---------------------------------------------------------------------------
__global__ __launch_bounds__(256) void k_cvtw(const float* __restrict__ Wk,
                                              __hip_bfloat16* __restrict__ wkb) {
  const int i = blockIdx.x * 256 + threadIdx.x;   // one float4 per thread
  float4 v = *reinterpret_cast<const float4*>(Wk + (size_t)i * 4);
  __hip_bfloat16 h[4];
  h[0] = __float2bfloat16(v.x); h[1] = __float2bfloat16(v.y);
  h[2] = __float2bfloat16(v.z); h[3] = __float2bfloat16(v.w);
  unsigned long long bits;
  __builtin_memcpy(&bits, h, 8);
  *reinterpret_cast<unsigned long long*>(wkb + (size_t)i * 4) = bits;
}

// ---------------------------------------------------------------------------
// K1: keys via MFMA. One wave per 16 keys (one depth): D = Wk[d] * states^T.
// ---------------------------------------------------------------------------
__global__ __launch_bounds__(64) void k_keys_mfma(const float* __restrict__ states,
                                                  const __hip_bfloat16* __restrict__ wkb,
                                                  const float* __restrict__ bk,
                                                  __hip_bfloat16* __restrict__ keys) {
  const int lane = threadIdx.x;
  const int c = lane & 15, hi = lane >> 4;
  int blk = blockIdx.x, d, t;
  if      (blk < 2)   { d = blk; t = 0; }
  else if (blk < 6)   { d = 2; t = blk - 2; }
  else if (blk < 22)  { d = 3; t = blk - 6; }
  else if (blk < 86)  { d = 4; t = blk - 22; }
  else if (blk < 342) { d = 5; t = blk - 86; }
  else                { d = 6; t = blk - 342; }
  const int cumArr[7] = {0, 4, 20, 84, 340, 1364, 5460};
  const int k0 = cumArr[d] + 16 * t;

  bf16x8 sb[4];
  const float* srow = states + (size_t)(k0 + c) * MDIM;
#pragma unroll
  for (int kf = 0; kf < 4; ++kf) {
    float4 a = *reinterpret_cast<const float4*>(srow + kf * 32 + hi * 8);
    float4 b = *reinterpret_cast<const float4*>(srow + kf * 32 + hi * 8 + 4);
    bf16x8 v;
    v[0] = (__bf16)a.x; v[1] = (__bf16)a.y; v[2] = (__bf16)a.z; v[3] = (__bf16)a.w;
    v[4] = (__bf16)b.x; v[5] = (__bf16)b.y; v[6] = (__bf16)b.z; v[7] = (__bf16)b.w;
    sb[kf] = v;
  }

  const __hip_bfloat16* wkd = wkb + (size_t)d * MDIM * MDIM;
  const float* bkd = bk + d * MDIM;
  const bool valid = (d > 0) || (c < 4);

#pragma unroll
  for (int ct = 0; ct < 8; ++ct) {
    bf16x8 aw[4];
    const __hip_bfloat16* wrow = wkd + (size_t)(ct * 16 + c) * MDIM;
#pragma unroll
    for (int kf = 0; kf < 4; ++kf)
      aw[kf] = *reinterpret_cast<const bf16x8*>(wrow + kf * 32 + hi * 8);
    f32x4 acc = {};
#pragma unroll
    for (int kf = 0; kf < 4; ++kf)
      acc = __builtin_amdgcn_mfma_f32_16x16x32_bf16(aw[kf], sb[kf], acc, 0, 0, 0);
    float4 bias = *reinterpret_cast<const float4*>(bkd + ct * 16 + hi * 4);
    __hip_bfloat16 hv[4];
    hv[0] = __float2bfloat16(fmaxf(acc[0] + bias.x, 0.f));
    hv[1] = __float2bfloat16(fmaxf(acc[1] + bias.y, 0.f));
    hv[2] = __float2bfloat16(fmaxf(acc[2] + bias.z, 0.f));
    hv[3] = __float2bfloat16(fmaxf(acc[3] + bias.w, 0.f));
    if (valid) {
      unsigned long long bits;
      __builtin_memcpy(&bits, hv, 8);
      *reinterpret_cast<unsigned long long*>(
          keys + (size_t)(k0 + c) * MDIM + ct * 16 + 4 * hi) = bits;
    }
  }
}

// ---------------------------------------------------------------------------
// K2: query[b][m] = bq[m] + dot(hidden[b][:64], Wq[m][:64])  -> bf16
// ---------------------------------------------------------------------------
__global__ __launch_bounds__(128) void k_query(const float* __restrict__ hidden,
                                               const float* __restrict__ Wq,
                                               const float* __restrict__ bq,
                                               __hip_bfloat16* __restrict__ query) {
  __shared__ __align__(16) float sH[4][CDIM];
  const int b0 = blockIdx.x * 4;
  const int m  = threadIdx.x;
  for (int idx = m; idx < 4 * CDIM; idx += 128)
    sH[idx >> 6][idx & 63] = hidden[(size_t)b0 * CDIM + idx];
  __syncthreads();
  const float4* wrow = (const float4*)(Wq + (size_t)m * CDIM);
  float acc0 = 0.f, acc1 = 0.f, acc2 = 0.f, acc3 = 0.f;
#pragma unroll
  for (int kq = 0; kq < CDIM / 4; ++kq) {
    float4 w = wrow[kq];
    float4 a = *(const float4*)&sH[0][kq * 4];
    float4 b = *(const float4*)&sH[1][kq * 4];
    float4 c = *(const float4*)&sH[2][kq * 4];
    float4 e = *(const float4*)&sH[3][kq * 4];
    acc0 += w.x * a.x + w.y * a.y + w.z * a.z + w.w * a.w;
    acc1 += w.x * b.x + w.y * b.y + w.z * b.z + w.w * b.w;
    acc2 += w.x * c.x + w.y * c.y + w.z * c.z + w.w * c.w;
    acc3 += w.x * e.x + w.y * e.y + w.z * e.z + w.w * e.w;
  }
  const float bias = bq[m];
  query[(size_t)(b0 + 0) * MDIM + m] = __float2bfloat16(acc0 + bias);
  query[(size_t)(b0 + 1) * MDIM + m] = __float2bfloat16(acc1 + bias);
  query[(size_t)(b0 + 2) * MDIM + m] = __float2bfloat16(acc2 + bias);
  query[(size_t)(b0 + 3) * MDIM + m] = __float2bfloat16(acc3 + bias);
}

// ---------------------------------------------------------------------------
// K3: subtree walker, v10 — depth-2 pipelined staging, barrier-free,
// no-max softmax. Wave = one depth-5 subtree (S5) x 16 b, 25 tiles.
// Per tile: ds_read(t) -> ds_write(t+1, loaded 2 tiles ago) -> issue
// global load (t+2) -> MFMA -> log-softmax (no max-sub; scores bounded) ->
// shuffle parent gather -> store / d7 LDS buffer. The early ds_write
// completes under tile t's compute, so the in-order DS pipe never stalls
// tile t+1's ds_read (was the serial-chain suspect). Zero __syncthreads.
// LDS/wave = 2x4KB keys + 4.35KB d7 buf -> 49.4KB/block, 3 blocks/CU.
// ---------------------------------------------------------------------------
#define D7STR 68   // padded row stride (floats)

__device__ __forceinline__ float gather_par(const f32x4 cp, int u, int lane) {
  const int src = u * 16 + (lane & 15);
  const float g0 = __shfl(cp[0], src, 64);
  const float g1 = __shfl(cp[1], src, 64);
  const float g2 = __shfl(cp[2], src, 64);
  const float g3 = __shfl(cp[3], src, 64);
  const int hi = lane >> 4;
  const float p01 = (hi & 1) ? g1 : g0;
  const float p23 = (hi & 1) ? g3 : g2;
  return (hi & 2) ? p23 : p01;
}

__device__ __forceinline__ void publish_tile(char* __restrict__ sKdst,
                                             const float4 (&stg)[4], int lane) {
  const int c = lane & 15;
#pragma unroll
  for (int i = 0; i < 4; ++i) {
    const int row = i * 4 + (lane >> 4);
    *reinterpret_cast<float4*>(sKdst + row * 256 + ((c ^ (row & 7)) << 4)) = stg[i];
  }
}

__device__ __forceinline__ void load_tile(const char* __restrict__ keyBytes,
                                          int base, float4 (&stg)[4], int lane) {
  const char* g = keyBytes + (size_t)base * 256 + lane * 16;
#pragma unroll
  for (int i = 0; i < 4; ++i)
    stg[i] = *reinterpret_cast<const float4*>(g + i * 1024);
}

__device__ __forceinline__ void tile_step(
    const char* __restrict__ keyBytes, char* __restrict__ sK, int& cur,
    bool writeValid, int loadBase, float4 (&stg)[4],
    const bf16x8 (&qf)[4], const f32x4* cumPrev, int u, f32x4& cumOut,
    float* __restrict__ oPtr, size_t span, bool doStore, bool d1mask,
    float* __restrict__ d7dst, int lane) {
  const int c = lane & 15, hi = lane >> 4;

  // 1) frag reads of current tile (buffer cur)
  bf16x8 af[4];
#pragma unroll
  for (int kf = 0; kf < 4; ++kf)
    af[kf] = *reinterpret_cast<const bf16x8*>(
        sK + cur * 4096 + c * 256 + (((kf * 4 + hi) ^ (c & 7)) << 4));

  // 2) publish tile t+1 (loaded two tiles ago) into the other buffer —
  //    completes under this tile's compute (in-order DS pipe)
  if (writeValid) publish_tile(sK + (cur ^ 1) * 4096, stg, lane);

  // 3) issue global load for tile t+2 (latency hidden across 2 tiles)
  if (loadBase >= 0) load_tile(keyBytes, loadBase, stg, lane);

  // 4) MFMA
  f32x4 acc = {};
  acc = __builtin_amdgcn_mfma_f32_16x16x32_bf16(af[0], qf[0], acc, 0, 0, 0);
  acc = __builtin_amdgcn_mfma_f32_16x16x32_bf16(af[1], qf[1], acc, 0, 0, 0);
  acc = __builtin_amdgcn_mfma_f32_16x16x32_bf16(af[2], qf[2], acc, 0, 0, 0);
  acc = __builtin_amdgcn_mfma_f32_16x16x32_bf16(af[3], qf[3], acc, 0, 0, 0);

  // 5) group-of-4 log-softmax WITHOUT max-subtraction (scores bounded ~|10|,
  //    f32 exp range is safe; removes serial fmax chain + 7 VALU)
  const float lse = __logf(__expf(acc[0]) + __expf(acc[1]) +
                           __expf(acc[2]) + __expf(acc[3]));
  float par = 0.f;
  if (cumPrev) par = gather_par(*cumPrev, u, lane);
  f32x4 cm;
  cm[0] = acc[0] - lse + par;
  cm[1] = acc[1] - lse + par;
  cm[2] = acc[2] - lse + par;
  cm[3] = acc[3] - lse + par;
  cumOut = cm;

  if (d7dst) {
    *reinterpret_cast<f32x4*>(d7dst + c * D7STR) = cm;
  } else if (doStore && (!d1mask || hi == 0)) {
    float4 o;
    o.x = cm[0]; o.y = cm[1]; o.z = cm[2]; o.w = cm[3];
    *reinterpret_cast<float4*>(oPtr + (size_t)c * span + hi * 4) = o;
  }
  cur ^= 1;
}

__global__ __launch_bounds__(256) void k_tree(const __hip_bfloat16* __restrict__ keys,
                                              const __hip_bfloat16* __restrict__ query,
                                              float* __restrict__ out, int B) {
  __shared__ __align__(16) float sKeys[4][2048];     // per-wave 2 x 4KB key bufs
  __shared__ __align__(16) float sD7[4][16 * D7STR]; // per-wave d6-group buffer

  const int tid  = threadIdx.x;
  const int lane = tid & 63;
  const int w    = tid >> 6;
  const int c    = lane & 15, hi = lane >> 4;

  const int S5  = blockIdx.x & 63;        // depth-5 subtree (XCD = S5%8)
  const int bg  = blockIdx.x >> 6;        // batch group (64 b per block)
  const int T4  = S5 >> 2;
  const int T3  = S5 >> 4;
  const int b0w = bg * 64 + w * 16;       // wave's 16-b base

  const char* keyBytes = reinterpret_cast<const char*>(keys);
  char* sK   = reinterpret_cast<char*>(&sKeys[w][0]);
  float* d7w = &sD7[w][0];

  // query B-frags (held in regs for all tiles)
  bf16x8 qf[4];
  {
    const __hip_bfloat16* qrow = query + (size_t)(b0w + c) * MDIM;
#pragma unroll
    for (int kf = 0; kf < 4; ++kf)
      qf[kf] = *reinterpret_cast<const bf16x8*>(qrow + kf * 32 + hi * 8);
  }

  // prologue: tile0 -> buf0; tile1 -> stg
  float4 stg[4];
  load_tile(keyBytes, 0, stg, lane);
  publish_tile(sK, stg, lane);
  load_tile(keyBytes, 4, stg, lane);
  int cur = 0;

  f32x4 c1, c2, c3, c4, c5, c6, c7;

  // d1 (t=0): load t+2 = d3
  tile_step(keyBytes, sK, cur, true, 20 + 16 * T3, stg, qf, nullptr, 0, c1,
            out + (size_t)b0w * 4, 4, S5 == 0, true, nullptr, lane);
  // d2 (t=1): load t+2 = d4
  tile_step(keyBytes, sK, cur, true, 84 + 16 * T4, stg, qf, &c1, 0, c2,
            out + (size_t)4 * B + (size_t)b0w * 16, 16, S5 == 0, false,
            nullptr, lane);
  // d3 (t=2): load t+2 = d5
  tile_step(keyBytes, sK, cur, true, 340 + 16 * S5, stg, qf, &c2, T3, c3,
            out + (size_t)20 * B + (size_t)b0w * 64 + 16 * T3, 64,
            (S5 & 15) == 0, false, nullptr, lane);
  // d4 (t=3): load t+2 = d6(0)
  tile_step(keyBytes, sK, cur, true, 1364 + 16 * (4 * S5), stg, qf, &c3, T4 & 3, c4,
            out + (size_t)84 * B + (size_t)b0w * 256 + 16 * T4, 256,
            (S5 & 3) == 0, false, nullptr, lane);
  // d5 (t=4): load t+2 = d7(0,0)
  tile_step(keyBytes, sK, cur, true, 5460 + 16 * (16 * S5), stg, qf, &c4, S5 & 3, c5,
            out + (size_t)340 * B + (size_t)b0w * 1024 + 16 * S5, 1024,
            true, false, nullptr, lane);

#pragma unroll
  for (int u5 = 0; u5 < 4; ++u5) {
    const int T6 = 4 * S5 + u5;
    // d6(u5): load t+2 = d7(u5,1)
    tile_step(keyBytes, sK, cur, true, 5460 + 16 * (16 * S5 + 4 * u5 + 1), stg,
              qf, &c5, u5, c6,
              out + (size_t)1364 * B + (size_t)b0w * 4096 + 16 * T6, 4096,
              true, false, nullptr, lane);
#pragma unroll
    for (int u6 = 0; u6 < 4; ++u6) {
      int nb;           // t+2 base
      if (u6 == 0)      nb = 5460 + 16 * (16 * S5 + 4 * u5 + 2);
      else if (u6 == 1) nb = 5460 + 16 * (16 * S5 + 4 * u5 + 3);
      else if (u6 == 2) nb = (u5 < 3) ? 1364 + 16 * (4 * S5 + u5 + 1) : -1;
      else              nb = (u5 < 3) ? 5460 + 16 * (16 * S5 + 4 * (u5 + 1)) : -1;
      const bool wv = !(u5 == 3 && u6 == 3);
      tile_step(keyBytes, sK, cur, wv, nb, stg, qf, &c6, u6, c7,
                nullptr, 0, false, false, d7w + u6 * 16 + hi * 4, lane);
    }
    // flush d6-group T6's d7: 4 instrs, each 16 rows x 256B contiguous
    {
      float* dst = out + (size_t)5460 * B + (size_t)b0w * 16384 + 64 * T6;
#pragma unroll
      for (int j = 0; j < 4; ++j) {
        const int r = j * 4 + hi;
        f32x4 v = *reinterpret_cast<const f32x4*>(d7w + r * D7STR + c * 4);
        float4 o;
        o.x = v[0]; o.y = v[1]; o.z = v[2]; o.w = v[3];
        *reinterpret_cast<float4*>(dst + (size_t)r * 16384 + c * 4) = o;
      }
    }
  }
}

// ---------------------------------------------------------------------------
extern "C" void kernel_launch(void* const* d_in, const int* in_sizes, int n_in,
                              void* d_out, int out_size, void* d_ws, size_t ws_size,
                              hipStream_t stream) {
  const float* hidden = (const float*)d_in[0];
  const float* Wq     = (const float*)d_in[1];
  const float* bq     = (const float*)d_in[2];
  const float* states = (const float*)d_in[3];
  const float* Wk     = (const float*)d_in[4];
  const float* bk     = (const float*)d_in[5];
  float* out = (float*)d_out;
  const int B = in_sizes[0] / CDIM;  // 4096

  __hip_bfloat16* keys  = (__hip_bfloat16*)d_ws;        // NKEYS*128 bf16
  __hip_bfloat16* query = keys + (size_t)NKEYS * MDIM;  // B*128 bf16
  __hip_bfloat16* wkb   = query + (size_t)B * MDIM;     // 7*128*128 bf16

  k_cvtw<<<(7 * MDIM * MDIM) / (256 * 4), 256, 0, stream>>>(Wk, wkb);
  k_query<<<B / 4, 128, 0, stream>>>(hidden, Wq, bq, query);
  k_keys_mfma<<<1366, 64, 0, stream>>>(states, wkb, bk, keys);

  // grid: subtree-fastest (XCD pinning): 64 subtrees x B/64 batch groups
  k_tree<<<(B / 64) * 64, 256, 0, stream>>>(keys, query, out, B);
}

// Round 11
// 122.751 us; speedup vs baseline: 1.1826x; 1.0657x over previous
//
#include <hip/hip_runtime.h>
#include <hip/hip_bf16.h>
#include <math.h>

#define MDIM 128
#define CDIM 64
#define NTILES 1366   // 16-key MFMA tiles: d1:1 d2:1 d3:4 d4:16 d5:64 d6:256 d7:1024
// tile blk index: d1=0, d2=1, d3=2+T3, d4=6+T4, d5=22+S5, d6=86+T6, d7=342+T7

typedef __attribute__((ext_vector_type(8))) __bf16 bf16x8;
typedef __attribute__((ext_vector_type(4))) float f32x4;

// ---------------------------------------------------------------------------
// K0: convert Wk (7x128x128 f32) -> bf16 once.
// ---------------------------------------------------------------------------
__global__ __launch_bounds__(256) void k_cvtw(const float* __restrict__ Wk,
                                              __hip_bfloat16* __restrict__ wkb) {
  const int i = blockIdx.x * 256 + threadIdx.x;   // one float4 per thread
  float4 v = *reinterpret_cast<const float4*>(Wk + (size_t)i * 4);
  __hip_bfloat16 h[4];
  h[0] = __float2bfloat16(v.x); h[1] = __float2bfloat16(v.y);
  h[2] = __float2bfloat16(v.z); h[3] = __float2bfloat16(v.w);
  unsigned long long bits;
  __builtin_memcpy(&bits, h, 8);
  *reinterpret_cast<unsigned long long*>(wkb + (size_t)i * 4) = bits;
}

// ---------------------------------------------------------------------------
// K1: keys via MFMA, output in FRAGMENT ORDER.
// One wave per 16-key tile (blk). Computes relu(Wk[d]*states^T + bk), then
// repacks through a small LDS transpose so the tree kernel's A-frag for
// lane L, chunk kf is keysF[(blk*4+kf)*64 + L] -> 1KB contiguous per load.
// ---------------------------------------------------------------------------
#define STR 144   // sT row stride in bf16 (16B-aligned rows)

__global__ __launch_bounds__(64) void k_keys_mfma(const float* __restrict__ states,
                                                  const __hip_bfloat16* __restrict__ wkb,
                                                  const float* __restrict__ bk,
                                                  bf16x8* __restrict__ keysF) {
  __shared__ __align__(16) __hip_bfloat16 sT[16 * STR];  // [key c][m]
  const int lane = threadIdx.x;
  const int c = lane & 15, hi = lane >> 4;
  int blk = blockIdx.x, d, t;
  if      (blk < 2)   { d = blk; t = 0; }
  else if (blk < 6)   { d = 2; t = blk - 2; }
  else if (blk < 22)  { d = 3; t = blk - 6; }
  else if (blk < 86)  { d = 4; t = blk - 22; }
  else if (blk < 342) { d = 5; t = blk - 86; }
  else                { d = 6; t = blk - 342; }
  const int cumArr[7] = {0, 4, 20, 84, 340, 1364, 5460};
  const int k0 = cumArr[d] + 16 * t;

  // B-frags: states rows (keys), f32 -> bf16 inline
  bf16x8 sb[4];
  const float* srow = states + (size_t)(k0 + c) * MDIM;
#pragma unroll
  for (int kf = 0; kf < 4; ++kf) {
    float4 a = *reinterpret_cast<const float4*>(srow + kf * 32 + hi * 8);
    float4 b = *reinterpret_cast<const float4*>(srow + kf * 32 + hi * 8 + 4);
    bf16x8 v;
    v[0] = (__bf16)a.x; v[1] = (__bf16)a.y; v[2] = (__bf16)a.z; v[3] = (__bf16)a.w;
    v[4] = (__bf16)b.x; v[5] = (__bf16)b.y; v[6] = (__bf16)b.z; v[7] = (__bf16)b.w;
    sb[kf] = v;
  }

  const __hip_bfloat16* wkd = wkb + (size_t)d * MDIM * MDIM;
  const float* bkd = bk + d * MDIM;

#pragma unroll
  for (int ct = 0; ct < 8; ++ct) {
    bf16x8 aw[4];
    const __hip_bfloat16* wrow = wkd + (size_t)(ct * 16 + c) * MDIM;
#pragma unroll
    for (int kf = 0; kf < 4; ++kf)
      aw[kf] = *reinterpret_cast<const bf16x8*>(wrow + kf * 32 + hi * 8);
    f32x4 acc = {};
#pragma unroll
    for (int kf = 0; kf < 4; ++kf)
      acc = __builtin_amdgcn_mfma_f32_16x16x32_bf16(aw[kf], sb[kf], acc, 0, 0, 0);
    // lane (c,hi) holds m = ct*16 + 4*hi + reg for key c
    float4 bias = *reinterpret_cast<const float4*>(bkd + ct * 16 + hi * 4);
    __hip_bfloat16 hv[4];
    hv[0] = __float2bfloat16(fmaxf(acc[0] + bias.x, 0.f));
    hv[1] = __float2bfloat16(fmaxf(acc[1] + bias.y, 0.f));
    hv[2] = __float2bfloat16(fmaxf(acc[2] + bias.z, 0.f));
    hv[3] = __float2bfloat16(fmaxf(acc[3] + bias.w, 0.f));
    unsigned long long bits;
    __builtin_memcpy(&bits, hv, 8);
    *reinterpret_cast<unsigned long long*>(&sT[c * STR + ct * 16 + 4 * hi]) = bits;
  }

  // repack: frag chunk (kf) for lane (c,hi) = keys[c][kf*32+hi*8 .. +8]
  // (intra-wave DS ops are in-order: reads see the writes above)
#pragma unroll
  for (int kf = 0; kf < 4; ++kf) {
    bf16x8 v = *reinterpret_cast<const bf16x8*>(&sT[c * STR + kf * 32 + hi * 8]);
    keysF[(size_t)(blk * 4 + kf) * 64 + lane] = v;   // 64 lanes x 16B = 1KB
  }
}

// ---------------------------------------------------------------------------
// K2: query[b][m] = bq[m] + dot(hidden[b][:64], Wq[m][:64])  -> bf16
// ---------------------------------------------------------------------------
__global__ __launch_bounds__(128) void k_query(const float* __restrict__ hidden,
                                               const float* __restrict__ Wq,
                                               const float* __restrict__ bq,
                                               __hip_bfloat16* __restrict__ query) {
  __shared__ __align__(16) float sH[4][CDIM];
  const int b0 = blockIdx.x * 4;
  const int m  = threadIdx.x;
  for (int idx = m; idx < 4 * CDIM; idx += 128)
    sH[idx >> 6][idx & 63] = hidden[(size_t)b0 * CDIM + idx];
  __syncthreads();
  const float4* wrow = (const float4*)(Wq + (size_t)m * CDIM);
  float acc0 = 0.f, acc1 = 0.f, acc2 = 0.f, acc3 = 0.f;
#pragma unroll
  for (int kq = 0; kq < CDIM / 4; ++kq) {
    float4 w = wrow[kq];
    float4 a = *(const float4*)&sH[0][kq * 4];
    float4 b = *(const float4*)&sH[1][kq * 4];
    float4 c = *(const float4*)&sH[2][kq * 4];
    float4 e = *(const float4*)&sH[3][kq * 4];
    acc0 += w.x * a.x + w.y * a.y + w.z * a.z + w.w * a.w;
    acc1 += w.x * b.x + w.y * b.y + w.z * b.z + w.w * b.w;
    acc2 += w.x * c.x + w.y * c.y + w.z * c.z + w.w * c.w;
    acc3 += w.x * e.x + w.y * e.y + w.z * e.z + w.w * e.w;
  }
  const float bias = bq[m];
  query[(size_t)(b0 + 0) * MDIM + m] = __float2bfloat16(acc0 + bias);
  query[(size_t)(b0 + 1) * MDIM + m] = __float2bfloat16(acc1 + bias);
  query[(size_t)(b0 + 2) * MDIM + m] = __float2bfloat16(acc2 + bias);
  query[(size_t)(b0 + 3) * MDIM + m] = __float2bfloat16(acc3 + bias);
}

// ---------------------------------------------------------------------------
// K3: subtree walker, v11 — zero key-staging LDS. Frag-ordered keys are
// loaded straight into registers (1KB coalesced per instruction, L2-hit via
// XCD pinning), register ping-pong fA/fB with depth-1 prefetch. LDS used
// only for the 4 parent-gather bpermutes and the d7 transpose buffer.
// Wave = one depth-5 subtree (S5) x 16 b, 25 tiles, barrier-free.
// ---------------------------------------------------------------------------
#define D7STR 68   // padded row stride (floats)

struct Frag { bf16x8 f[4]; };

__device__ __forceinline__ void load_frags(const bf16x8* __restrict__ kF,
                                           int blk, Frag& fr, int lane) {
#pragma unroll
  for (int kf = 0; kf < 4; ++kf)
    fr.f[kf] = kF[(size_t)(blk * 4 + kf) * 64 + lane];
}

__device__ __forceinline__ float gather_par(const f32x4 cp, int u, int lane) {
  const int src = u * 16 + (lane & 15);
  const float g0 = __shfl(cp[0], src, 64);
  const float g1 = __shfl(cp[1], src, 64);
  const float g2 = __shfl(cp[2], src, 64);
  const float g3 = __shfl(cp[3], src, 64);
  const int hi = lane >> 4;
  const float p01 = (hi & 1) ? g1 : g0;
  const float p23 = (hi & 1) ? g3 : g2;
  return (hi & 2) ? p23 : p01;
}

__device__ __forceinline__ void tile_step(
    const bf16x8* __restrict__ kF, const Frag& cur, int nextBlk, Frag& nxt,
    const bf16x8 (&qf)[4], const f32x4* cumPrev, int u, f32x4& cumOut,
    float* __restrict__ oPtr, size_t span, bool doStore, bool d1mask,
    float* __restrict__ d7dst, int lane) {
  const int c = lane & 15, hi = lane >> 4;

  // prefetch next tile's frags (L2 latency hides under this tile's compute)
  if (nextBlk >= 0) load_frags(kF, nextBlk, nxt, lane);

  f32x4 acc = {};
  acc = __builtin_amdgcn_mfma_f32_16x16x32_bf16(cur.f[0], qf[0], acc, 0, 0, 0);
  acc = __builtin_amdgcn_mfma_f32_16x16x32_bf16(cur.f[1], qf[1], acc, 0, 0, 0);
  acc = __builtin_amdgcn_mfma_f32_16x16x32_bf16(cur.f[2], qf[2], acc, 0, 0, 0);
  acc = __builtin_amdgcn_mfma_f32_16x16x32_bf16(cur.f[3], qf[3], acc, 0, 0, 0);

  // group-of-4 log-softmax without max-subtraction (scores bounded)
  const float lse = __logf(__expf(acc[0]) + __expf(acc[1]) +
                           __expf(acc[2]) + __expf(acc[3]));
  float par = 0.f;
  if (cumPrev) par = gather_par(*cumPrev, u, lane);
  f32x4 cm;
  cm[0] = acc[0] - lse + par;
  cm[1] = acc[1] - lse + par;
  cm[2] = acc[2] - lse + par;
  cm[3] = acc[3] - lse + par;
  cumOut = cm;

  if (d7dst) {
    *reinterpret_cast<f32x4*>(d7dst + c * D7STR) = cm;
  } else if (doStore && (!d1mask || hi == 0)) {
    float4 o;
    o.x = cm[0]; o.y = cm[1]; o.z = cm[2]; o.w = cm[3];
    *reinterpret_cast<float4*>(oPtr + (size_t)c * span + hi * 4) = o;
  }
}

__global__ __launch_bounds__(256) void k_tree(const bf16x8* __restrict__ kF,
                                              const __hip_bfloat16* __restrict__ query,
                                              float* __restrict__ out, int B) {
  __shared__ __align__(16) float sD7[4][16 * D7STR]; // per-wave d6-group buffer

  const int tid  = threadIdx.x;
  const int lane = tid & 63;
  const int w    = tid >> 6;
  const int c    = lane & 15, hi = lane >> 4;

  const int S5  = blockIdx.x & 63;        // depth-5 subtree (XCD = S5%8)
  const int bg  = blockIdx.x >> 6;        // batch group (64 b per block)
  const int T4  = S5 >> 2;
  const int T3  = S5 >> 4;
  const int b0w = bg * 64 + w * 16;       // wave's 16-b base

  float* d7w = &sD7[w][0];

  // query B-frags (held in regs for all tiles)
  bf16x8 qf[4];
  {
    const __hip_bfloat16* qrow = query + (size_t)(b0w + c) * MDIM;
#pragma unroll
    for (int kf = 0; kf < 4; ++kf)
      qf[kf] = *reinterpret_cast<const bf16x8*>(qrow + kf * 32 + hi * 8);
  }

  Frag fA, fB;
  load_frags(kF, 0, fA, lane);            // d1 tile

  f32x4 c1, c2, c3, c4, c5, c6, c7;

  // d1 (blk 0): next d2 (blk 1)
  tile_step(kF, fA, 1, fB, qf, nullptr, 0, c1,
            out + (size_t)b0w * 4, 4, S5 == 0, true, nullptr, lane);
  // d2: next d3
  tile_step(kF, fB, 2 + T3, fA, qf, &c1, 0, c2,
            out + (size_t)4 * B + (size_t)b0w * 16, 16, S5 == 0, false,
            nullptr, lane);
  // d3: next d4
  tile_step(kF, fA, 6 + T4, fB, qf, &c2, T3, c3,
            out + (size_t)20 * B + (size_t)b0w * 64 + 16 * T3, 64,
            (S5 & 15) == 0, false, nullptr, lane);
  // d4: next d5
  tile_step(kF, fB, 22 + S5, fA, qf, &c3, T4 & 3, c4,
            out + (size_t)84 * B + (size_t)b0w * 256 + 16 * T4, 256,
            (S5 & 3) == 0, false, nullptr, lane);
  // d5: next d6(u5=0)
  tile_step(kF, fA, 86 + 4 * S5, fB, qf, &c4, S5 & 3, c5,
            out + (size_t)340 * B + (size_t)b0w * 1024 + 16 * S5, 1024,
            true, false, nullptr, lane);

  // d6/d7 groups. Each group = 5 tile_steps; frag parity flips per group.
#pragma unroll
  for (int u5p = 0; u5p < 2; ++u5p) {
#pragma unroll
    for (int half = 0; half < 2; ++half) {
      const int u5 = u5p * 2 + half;
      Frag& f0 = (half == 0) ? fB : fA;   // compile-time after unroll
      Frag& f1 = (half == 0) ? fA : fB;
      const int T6 = 4 * S5 + u5;
      const int d7b = 342 + 16 * S5 + 4 * u5;   // first d7 blk of this group
      // d6: next d7(u6=0)
      tile_step(kF, f0, d7b, f1, qf, &c5, u5, c6,
                out + (size_t)1364 * B + (size_t)b0w * 4096 + 16 * T6, 4096,
                true, false, nullptr, lane);
      // d7 u6=0..3
      tile_step(kF, f1, d7b + 1, f0, qf, &c6, 0, c7,
                nullptr, 0, false, false, d7w + 0 * 16 + hi * 4, lane);
      tile_step(kF, f0, d7b + 2, f1, qf, &c6, 1, c7,
                nullptr, 0, false, false, d7w + 1 * 16 + hi * 4, lane);
      tile_step(kF, f1, d7b + 3, f0, qf, &c6, 2, c7,
                nullptr, 0, false, false, d7w + 2 * 16 + hi * 4, lane);
      tile_step(kF, f0, (u5 < 3) ? (86 + 4 * S5 + u5 + 1) : -1, f1, qf, &c6, 3, c7,
                nullptr, 0, false, false, d7w + 3 * 16 + hi * 4, lane);
      // flush d6-group T6's d7: 4 instrs, each 16 rows x 256B contiguous
      {
        float* dst = out + (size_t)5460 * B + (size_t)b0w * 16384 + 64 * T6;
#pragma unroll
        for (int j = 0; j < 4; ++j) {
          const int r = j * 4 + hi;
          f32x4 v = *reinterpret_cast<const f32x4*>(d7w + r * D7STR + c * 4);
          float4 o;
          o.x = v[0]; o.y = v[1]; o.z = v[2]; o.w = v[3];
          *reinterpret_cast<float4*>(dst + (size_t)r * 16384 + c * 4) = o;
        }
      }
    }
  }
}

// ---------------------------------------------------------------------------
extern "C" void kernel_launch(void* const* d_in, const int* in_sizes, int n_in,
                              void* d_out, int out_size, void* d_ws, size_t ws_size,
                              hipStream_t stream) {
  const float* hidden = (const float*)d_in[0];
  const float* Wq     = (const float*)d_in[1];
  const float* bq     = (const float*)d_in[2];
  const float* states = (const float*)d_in[3];
  const float* Wk     = (const float*)d_in[4];
  const float* bk     = (const float*)d_in[5];
  float* out = (float*)d_out;
  const int B = in_sizes[0] / CDIM;  // 4096

  __hip_bfloat16* base  = (__hip_bfloat16*)d_ws;
  bf16x8* keysF = (bf16x8*)base;                              // 1366*4*64*16B = 5.6MB
  __hip_bfloat16* query = base + (size_t)NTILES * 4 * 64 * 8; // B*128 bf16
  __hip_bfloat16* wkb   = query + (size_t)B * MDIM;           // 7*128*128 bf16

  k_cvtw<<<(7 * MDIM * MDIM) / (256 * 4), 256, 0, stream>>>(Wk, wkb);
  k_query<<<B / 4, 128, 0, stream>>>(hidden, Wq, bq, query);
  k_keys_mfma<<<NTILES, 64, 0, stream>>>(states, wkb, bk, keysF);

  // grid: subtree-fastest (XCD pinning): 64 subtrees x B/64 batch groups
  k_tree<<<(B / 64) * 64, 256, 0, stream>>>(keysF, query, out, B);
}

// Round 12
// 119.389 us; speedup vs baseline: 1.2159x; 1.0282x over previous
//
#include <hip/hip_runtime.h>
#include <hip/hip_bf16.h>
#include <math.h>

#define MDIM 128
#define CDIM 64
#define NTILES 1366   // 16-key MFMA tiles: d1:1 d2:1 d3:4 d4:16 d5:64 d6:256 d7:1024
// tile blk index: d1=0, d2=1, d3=2+T3, d4=6+T4, d5=22+S5, d6=86+T6, d7=342+T7

typedef __attribute__((ext_vector_type(8))) __bf16 bf16x8;
typedef __attribute__((ext_vector_type(4))) float f32x4;

// ---------------------------------------------------------------------------
// K0: convert Wk (7x128x128 f32) -> bf16 once.
// ---------------------------------------------------------------------------
__global__ __launch_bounds__(256) void k_cvtw(const float* __restrict__ Wk,
                                              __hip_bfloat16* __restrict__ wkb) {
  const int i = blockIdx.x * 256 + threadIdx.x;   // one float4 per thread
  float4 v = *reinterpret_cast<const float4*>(Wk + (size_t)i * 4);
  __hip_bfloat16 h[4];
  h[0] = __float2bfloat16(v.x); h[1] = __float2bfloat16(v.y);
  h[2] = __float2bfloat16(v.z); h[3] = __float2bfloat16(v.w);
  unsigned long long bits;
  __builtin_memcpy(&bits, h, 8);
  *reinterpret_cast<unsigned long long*>(wkb + (size_t)i * 4) = bits;
}

// ---------------------------------------------------------------------------
// K1: keys via MFMA, output in FRAGMENT ORDER.
// One wave per 16-key tile (blk); repack via small LDS transpose so the
// tree kernel's A-frag (lane L, chunk kf) = keysF[(blk*4+kf)*64 + L].
// ---------------------------------------------------------------------------
#define STR 144   // sT row stride in bf16 (16B-aligned rows)

__global__ __launch_bounds__(64) void k_keys_mfma(const float* __restrict__ states,
                                                  const __hip_bfloat16* __restrict__ wkb,
                                                  const float* __restrict__ bk,
                                                  bf16x8* __restrict__ keysF) {
  __shared__ __align__(16) __hip_bfloat16 sT[16 * STR];  // [key c][m]
  const int lane = threadIdx.x;
  const int c = lane & 15, hi = lane >> 4;
  int blk = blockIdx.x, d, t;
  if      (blk < 2)   { d = blk; t = 0; }
  else if (blk < 6)   { d = 2; t = blk - 2; }
  else if (blk < 22)  { d = 3; t = blk - 6; }
  else if (blk < 86)  { d = 4; t = blk - 22; }
  else if (blk < 342) { d = 5; t = blk - 86; }
  else                { d = 6; t = blk - 342; }
  const int cumArr[7] = {0, 4, 20, 84, 340, 1364, 5460};
  const int k0 = cumArr[d] + 16 * t;

  bf16x8 sb[4];
  const float* srow = states + (size_t)(k0 + c) * MDIM;
#pragma unroll
  for (int kf = 0; kf < 4; ++kf) {
    float4 a = *reinterpret_cast<const float4*>(srow + kf * 32 + hi * 8);
    float4 b = *reinterpret_cast<const float4*>(srow + kf * 32 + hi * 8 + 4);
    bf16x8 v;
    v[0] = (__bf16)a.x; v[1] = (__bf16)a.y; v[2] = (__bf16)a.z; v[3] = (__bf16)a.w;
    v[4] = (__bf16)b.x; v[5] = (__bf16)b.y; v[6] = (__bf16)b.z; v[7] = (__bf16)b.w;
    sb[kf] = v;
  }

  const __hip_bfloat16* wkd = wkb + (size_t)d * MDIM * MDIM;
  const float* bkd = bk + d * MDIM;

#pragma unroll
  for (int ct = 0; ct < 8; ++ct) {
    bf16x8 aw[4];
    const __hip_bfloat16* wrow = wkd + (size_t)(ct * 16 + c) * MDIM;
#pragma unroll
    for (int kf = 0; kf < 4; ++kf)
      aw[kf] = *reinterpret_cast<const bf16x8*>(wrow + kf * 32 + hi * 8);
    f32x4 acc = {};
#pragma unroll
    for (int kf = 0; kf < 4; ++kf)
      acc = __builtin_amdgcn_mfma_f32_16x16x32_bf16(aw[kf], sb[kf], acc, 0, 0, 0);
    float4 bias = *reinterpret_cast<const float4*>(bkd + ct * 16 + hi * 4);
    __hip_bfloat16 hv[4];
    hv[0] = __float2bfloat16(fmaxf(acc[0] + bias.x, 0.f));
    hv[1] = __float2bfloat16(fmaxf(acc[1] + bias.y, 0.f));
    hv[2] = __float2bfloat16(fmaxf(acc[2] + bias.z, 0.f));
    hv[3] = __float2bfloat16(fmaxf(acc[3] + bias.w, 0.f));
    unsigned long long bits;
    __builtin_memcpy(&bits, hv, 8);
    *reinterpret_cast<unsigned long long*>(&sT[c * STR + ct * 16 + 4 * hi]) = bits;
  }

#pragma unroll
  for (int kf = 0; kf < 4; ++kf) {
    bf16x8 v = *reinterpret_cast<const bf16x8*>(&sT[c * STR + kf * 32 + hi * 8]);
    keysF[(size_t)(blk * 4 + kf) * 64 + lane] = v;   // 64 lanes x 16B = 1KB
  }
}

// ---------------------------------------------------------------------------
// K2: query[b][m] = bq[m] + dot(hidden[b][:64], Wq[m][:64])  -> bf16
// ---------------------------------------------------------------------------
__global__ __launch_bounds__(128) void k_query(const float* __restrict__ hidden,
                                               const float* __restrict__ Wq,
                                               const float* __restrict__ bq,
                                               __hip_bfloat16* __restrict__ query) {
  __shared__ __align__(16) float sH[4][CDIM];
  const int b0 = blockIdx.x * 4;
  const int m  = threadIdx.x;
  for (int idx = m; idx < 4 * CDIM; idx += 128)
    sH[idx >> 6][idx & 63] = hidden[(size_t)b0 * CDIM + idx];
  __syncthreads();
  const float4* wrow = (const float4*)(Wq + (size_t)m * CDIM);
  float acc0 = 0.f, acc1 = 0.f, acc2 = 0.f, acc3 = 0.f;
#pragma unroll
  for (int kq = 0; kq < CDIM / 4; ++kq) {
    float4 w = wrow[kq];
    float4 a = *(const float4*)&sH[0][kq * 4];
    float4 b = *(const float4*)&sH[1][kq * 4];
    float4 c = *(const float4*)&sH[2][kq * 4];
    float4 e = *(const float4*)&sH[3][kq * 4];
    acc0 += w.x * a.x + w.y * a.y + w.z * a.z + w.w * a.w;
    acc1 += w.x * b.x + w.y * b.y + w.z * b.z + w.w * b.w;
    acc2 += w.x * c.x + w.y * c.y + w.z * c.z + w.w * c.w;
    acc3 += w.x * e.x + w.y * e.y + w.z * e.z + w.w * e.w;
  }
  const float bias = bq[m];
  query[(size_t)(b0 + 0) * MDIM + m] = __float2bfloat16(acc0 + bias);
  query[(size_t)(b0 + 1) * MDIM + m] = __float2bfloat16(acc1 + bias);
  query[(size_t)(b0 + 2) * MDIM + m] = __float2bfloat16(acc2 + bias);
  query[(size_t)(b0 + 3) * MDIM + m] = __float2bfloat16(acc3 + bias);
}

// ---------------------------------------------------------------------------
// K3: subtree walker, v12 — 32 b per wave (2 b-tiles share every frag load:
// halves the L2 read stream, the suspected co-limiter). Zero key-staging
// LDS; frag-ordered keys straight to registers (1KB coalesced, XCD-pinned
// L2); register ping-pong prefetch; no-max softmax; shuffle parent gather;
// d7 via per-wave [32 b][64 key] LDS transpose buffer (stride 68, <=2-way
// banked both phases), flushed per d6 group as 8 instrs x 4 x 256B runs.
// ---------------------------------------------------------------------------
#define D7STR 68   // padded row stride (floats)

struct Frag { bf16x8 f[4]; };

__device__ __forceinline__ void load_frags(const bf16x8* __restrict__ kF,
                                           int blk, Frag& fr, int lane) {
#pragma unroll
  for (int kf = 0; kf < 4; ++kf)
    fr.f[kf] = kF[(size_t)(blk * 4 + kf) * 64 + lane];
}

__device__ __forceinline__ float gather_par(const f32x4 cp, int u, int lane) {
  const int src = u * 16 + (lane & 15);
  const float g0 = __shfl(cp[0], src, 64);
  const float g1 = __shfl(cp[1], src, 64);
  const float g2 = __shfl(cp[2], src, 64);
  const float g3 = __shfl(cp[3], src, 64);
  const int hi = lane >> 4;
  const float p01 = (hi & 1) ? g1 : g0;
  const float p23 = (hi & 1) ? g3 : g2;
  return (hi & 2) ? p23 : p01;
}

__device__ __forceinline__ void tile_step(
    const bf16x8* __restrict__ kF, const Frag& cur, int nextBlk, Frag& nxt,
    const bf16x8 (&qf)[2][4], const f32x4* cumPrev, int u, f32x4 (&cumOut)[2],
    float* __restrict__ oPtr, size_t span, bool doStore, bool d1mask,
    float* __restrict__ d7dst, int lane) {
  const int c = lane & 15, hi = lane >> 4;

  // prefetch next tile's frags (L2 latency hides under this tile's compute)
  if (nextBlk >= 0) load_frags(kF, nextBlk, nxt, lane);

#pragma unroll
  for (int bt = 0; bt < 2; ++bt) {
    f32x4 acc = {};
    acc = __builtin_amdgcn_mfma_f32_16x16x32_bf16(cur.f[0], qf[bt][0], acc, 0, 0, 0);
    acc = __builtin_amdgcn_mfma_f32_16x16x32_bf16(cur.f[1], qf[bt][1], acc, 0, 0, 0);
    acc = __builtin_amdgcn_mfma_f32_16x16x32_bf16(cur.f[2], qf[bt][2], acc, 0, 0, 0);
    acc = __builtin_amdgcn_mfma_f32_16x16x32_bf16(cur.f[3], qf[bt][3], acc, 0, 0, 0);

    // group-of-4 log-softmax without max-subtraction (scores bounded)
    const float lse = __logf(__expf(acc[0]) + __expf(acc[1]) +
                             __expf(acc[2]) + __expf(acc[3]));
    float par = 0.f;
    if (cumPrev) par = gather_par(cumPrev[bt], u, lane);
    f32x4 cm;
    cm[0] = acc[0] - lse + par;
    cm[1] = acc[1] - lse + par;
    cm[2] = acc[2] - lse + par;
    cm[3] = acc[3] - lse + par;
    cumOut[bt] = cm;

    if (d7dst) {
      *reinterpret_cast<f32x4*>(d7dst + (bt * 16 + c) * D7STR) = cm;
    } else if (doStore && (!d1mask || hi == 0)) {
      float4 o;
      o.x = cm[0]; o.y = cm[1]; o.z = cm[2]; o.w = cm[3];
      *reinterpret_cast<float4*>(oPtr + (size_t)(bt * 16 + c) * span + hi * 4) = o;
    }
  }
}

__global__ __launch_bounds__(256) void k_tree(const bf16x8* __restrict__ kF,
                                              const __hip_bfloat16* __restrict__ query,
                                              float* __restrict__ out, int B) {
  __shared__ __align__(16) float sD7[4][32 * D7STR]; // per-wave d6-group buffer

  const int tid  = threadIdx.x;
  const int lane = tid & 63;
  const int w    = tid >> 6;
  const int c    = lane & 15, hi = lane >> 4;

  const int S5  = blockIdx.x & 63;        // depth-5 subtree (XCD = S5%8)
  const int bg  = blockIdx.x >> 6;        // batch group (128 b per block)
  const int T4  = S5 >> 2;
  const int T3  = S5 >> 4;
  const int b0w = bg * 128 + w * 32;      // wave's 32-b base

  float* d7w = &sD7[w][0];

  // query B-frags for both b-tiles (held in regs for all tiles)
  bf16x8 qf[2][4];
#pragma unroll
  for (int bt = 0; bt < 2; ++bt) {
    const __hip_bfloat16* qrow = query + (size_t)(b0w + bt * 16 + c) * MDIM;
#pragma unroll
    for (int kf = 0; kf < 4; ++kf)
      qf[bt][kf] = *reinterpret_cast<const bf16x8*>(qrow + kf * 32 + hi * 8);
  }

  Frag fA, fB;
  load_frags(kF, 0, fA, lane);            // d1 tile

  f32x4 c1[2], c2[2], c3[2], c4[2], c5[2], c6[2], c7[2];

  // d1 (blk 0): next d2 (blk 1)
  tile_step(kF, fA, 1, fB, qf, nullptr, 0, c1,
            out + (size_t)b0w * 4, 4, S5 == 0, true, nullptr, lane);
  // d2: next d3
  tile_step(kF, fB, 2 + T3, fA, qf, c1, 0, c2,
            out + (size_t)4 * B + (size_t)b0w * 16, 16, S5 == 0, false,
            nullptr, lane);
  // d3: next d4
  tile_step(kF, fA, 6 + T4, fB, qf, c2, T3, c3,
            out + (size_t)20 * B + (size_t)b0w * 64 + 16 * T3, 64,
            (S5 & 15) == 0, false, nullptr, lane);
  // d4: next d5
  tile_step(kF, fB, 22 + S5, fA, qf, c3, T4 & 3, c4,
            out + (size_t)84 * B + (size_t)b0w * 256 + 16 * T4, 256,
            (S5 & 3) == 0, false, nullptr, lane);
  // d5: next d6(u5=0)
  tile_step(kF, fA, 86 + 4 * S5, fB, qf, c4, S5 & 3, c5,
            out + (size_t)340 * B + (size_t)b0w * 1024 + 16 * S5, 1024,
            true, false, nullptr, lane);

  // d6/d7 groups. Each group = 5 tile_steps; frag parity flips per group.
#pragma unroll
  for (int u5p = 0; u5p < 2; ++u5p) {
#pragma unroll
    for (int half = 0; half < 2; ++half) {
      const int u5 = u5p * 2 + half;
      Frag& f0 = (half == 0) ? fB : fA;   // compile-time after unroll
      Frag& f1 = (half == 0) ? fA : fB;
      const int T6 = 4 * S5 + u5;
      const int d7b = 342 + 16 * S5 + 4 * u5;   // first d7 blk of this group
      // d6: next d7(u6=0)
      tile_step(kF, f0, d7b, f1, qf, c5, u5, c6,
                out + (size_t)1364 * B + (size_t)b0w * 4096 + 16 * T6, 4096,
                true, false, nullptr, lane);
      // d7 u6=0..3
      tile_step(kF, f1, d7b + 1, f0, qf, c6, 0, c7,
                nullptr, 0, false, false, d7w + 0 * 16 + hi * 4, lane);
      tile_step(kF, f0, d7b + 2, f1, qf, c6, 1, c7,
                nullptr, 0, false, false, d7w + 1 * 16 + hi * 4, lane);
      tile_step(kF, f1, d7b + 3, f0, qf, c6, 2, c7,
                nullptr, 0, false, false, d7w + 2 * 16 + hi * 4, lane);
      tile_step(kF, f0, (u5 < 3) ? (86 + 4 * S5 + u5 + 1) : -1, f1, qf, c6, 3, c7,
                nullptr, 0, false, false, d7w + 3 * 16 + hi * 4, lane);
      // flush d6-group T6's d7: 32 b-rows; 8 instrs x 4 rows x 256B runs
      {
        float* dst = out + (size_t)5460 * B + (size_t)b0w * 16384 + 64 * T6;
#pragma unroll
        for (int j = 0; j < 8; ++j) {
          const int r = j * 4 + hi;
          f32x4 v = *reinterpret_cast<const f32x4*>(d7w + r * D7STR + c * 4);
          float4 o;
          o.x = v[0]; o.y = v[1]; o.z = v[2]; o.w = v[3];
          *reinterpret_cast<float4*>(dst + (size_t)r * 16384 + c * 4) = o;
        }
      }
    }
  }
}

// ---------------------------------------------------------------------------
extern "C" void kernel_launch(void* const* d_in, const int* in_sizes, int n_in,
                              void* d_out, int out_size, void* d_ws, size_t ws_size,
                              hipStream_t stream) {
  const float* hidden = (const float*)d_in[0];
  const float* Wq     = (const float*)d_in[1];
  const float* bq     = (const float*)d_in[2];
  const float* states = (const float*)d_in[3];
  const float* Wk     = (const float*)d_in[4];
  const float* bk     = (const float*)d_in[5];
  float* out = (float*)d_out;
  const int B = in_sizes[0] / CDIM;  // 4096

  __hip_bfloat16* base  = (__hip_bfloat16*)d_ws;
  bf16x8* keysF = (bf16x8*)base;                              // 5.6MB frag-ordered
  __hip_bfloat16* query = base + (size_t)NTILES * 4 * 64 * 8; // B*128 bf16
  __hip_bfloat16* wkb   = query + (size_t)B * MDIM;           // 7*128*128 bf16

  k_cvtw<<<(7 * MDIM * MDIM) / (256 * 4), 256, 0, stream>>>(Wk, wkb);
  k_query<<<B / 4, 128, 0, stream>>>(hidden, Wq, bq, query);
  k_keys_mfma<<<NTILES, 64, 0, stream>>>(states, wkb, bk, keysF);

  // grid: subtree-fastest (XCD pinning): 64 subtrees x B/128 batch groups
  k_tree<<<(B / 128) * 64, 256, 0, stream>>>(keysF, query, out, B);
}

// Round 13
// 106.462 us; speedup vs baseline: 1.3635x; 1.1214x over previous
//
#include <hip/hip_runtime.h>
#include <hip/hip_bf16.h>
#include <math.h>

#define MDIM 128
#define CDIM 64
#define NTILES 1366   // 16-key MFMA tiles: d1:1 d2:1 d3:4 d4:16 d5:64 d6:256 d7:1024
// tile blk index: d1=0, d2=1, d3=2+T3, d4=6+T4, d5=22+S5, d6=86+T6, d7=342+T7

typedef __attribute__((ext_vector_type(8))) __bf16 bf16x8;
typedef __attribute__((ext_vector_type(4))) float f32x4;

// ---------------------------------------------------------------------------
// K0: convert Wk (7x128x128 f32) -> bf16 once.
// ---------------------------------------------------------------------------
__global__ __launch_bounds__(256) void k_cvtw(const float* __restrict__ Wk,
                                              __hip_bfloat16* __restrict__ wkb) {
  const int i = blockIdx.x * 256 + threadIdx.x;   // one float4 per thread
  float4 v = *reinterpret_cast<const float4*>(Wk + (size_t)i * 4);
  __hip_bfloat16 h[4];
  h[0] = __float2bfloat16(v.x); h[1] = __float2bfloat16(v.y);
  h[2] = __float2bfloat16(v.z); h[3] = __float2bfloat16(v.w);
  unsigned long long bits;
  __builtin_memcpy(&bits, h, 8);
  *reinterpret_cast<unsigned long long*>(wkb + (size_t)i * 4) = bits;
}

// ---------------------------------------------------------------------------
// K1: keys via MFMA, output in FRAGMENT ORDER.
// ---------------------------------------------------------------------------
#define STR 144   // sT row stride in bf16 (16B-aligned rows)

__global__ __launch_bounds__(64) void k_keys_mfma(const float* __restrict__ states,
                                                  const __hip_bfloat16* __restrict__ wkb,
                                                  const float* __restrict__ bk,
                                                  bf16x8* __restrict__ keysF) {
  __shared__ __align__(16) __hip_bfloat16 sT[16 * STR];  // [key c][m]
  const int lane = threadIdx.x;
  const int c = lane & 15, hi = lane >> 4;
  int blk = blockIdx.x, d, t;
  if      (blk < 2)   { d = blk; t = 0; }
  else if (blk < 6)   { d = 2; t = blk - 2; }
  else if (blk < 22)  { d = 3; t = blk - 6; }
  else if (blk < 86)  { d = 4; t = blk - 22; }
  else if (blk < 342) { d = 5; t = blk - 86; }
  else                { d = 6; t = blk - 342; }
  const int cumArr[7] = {0, 4, 20, 84, 340, 1364, 5460};
  const int k0 = cumArr[d] + 16 * t;

  bf16x8 sb[4];
  const float* srow = states + (size_t)(k0 + c) * MDIM;
#pragma unroll
  for (int kf = 0; kf < 4; ++kf) {
    float4 a = *reinterpret_cast<const float4*>(srow + kf * 32 + hi * 8);
    float4 b = *reinterpret_cast<const float4*>(srow + kf * 32 + hi * 8 + 4);
    bf16x8 v;
    v[0] = (__bf16)a.x; v[1] = (__bf16)a.y; v[2] = (__bf16)a.z; v[3] = (__bf16)a.w;
    v[4] = (__bf16)b.x; v[5] = (__bf16)b.y; v[6] = (__bf16)b.z; v[7] = (__bf16)b.w;
    sb[kf] = v;
  }

  const __hip_bfloat16* wkd = wkb + (size_t)d * MDIM * MDIM;
  const float* bkd = bk + d * MDIM;

#pragma unroll
  for (int ct = 0; ct < 8; ++ct) {
    bf16x8 aw[4];
    const __hip_bfloat16* wrow = wkd + (size_t)(ct * 16 + c) * MDIM;
#pragma unroll
    for (int kf = 0; kf < 4; ++kf)
      aw[kf] = *reinterpret_cast<const bf16x8*>(wrow + kf * 32 + hi * 8);
    f32x4 acc = {};
#pragma unroll
    for (int kf = 0; kf < 4; ++kf)
      acc = __builtin_amdgcn_mfma_f32_16x16x32_bf16(aw[kf], sb[kf], acc, 0, 0, 0);
    float4 bias = *reinterpret_cast<const float4*>(bkd + ct * 16 + hi * 4);
    __hip_bfloat16 hv[4];
    hv[0] = __float2bfloat16(fmaxf(acc[0] + bias.x, 0.f));
    hv[1] = __float2bfloat16(fmaxf(acc[1] + bias.y, 0.f));
    hv[2] = __float2bfloat16(fmaxf(acc[2] + bias.z, 0.f));
    hv[3] = __float2bfloat16(fmaxf(acc[3] + bias.w, 0.f));
    unsigned long long bits;
    __builtin_memcpy(&bits, hv, 8);
    *reinterpret_cast<unsigned long long*>(&sT[c * STR + ct * 16 + 4 * hi]) = bits;
  }

#pragma unroll
  for (int kf = 0; kf < 4; ++kf) {
    bf16x8 v = *reinterpret_cast<const bf16x8*>(&sT[c * STR + kf * 32 + hi * 8]);
    keysF[(size_t)(blk * 4 + kf) * 64 + lane] = v;   // 64 lanes x 16B = 1KB
  }
}

// ---------------------------------------------------------------------------
// K2: query[b][m] = bq[m] + dot(hidden[b][:64], Wq[m][:64])  -> bf16
// ---------------------------------------------------------------------------
__global__ __launch_bounds__(128) void k_query(const float* __restrict__ hidden,
                                               const float* __restrict__ Wq,
                                               const float* __restrict__ bq,
                                               __hip_bfloat16* __restrict__ query) {
  __shared__ __align__(16) float sH[4][CDIM];
  const int b0 = blockIdx.x * 4;
  const int m  = threadIdx.x;
  for (int idx = m; idx < 4 * CDIM; idx += 128)
    sH[idx >> 6][idx & 63] = hidden[(size_t)b0 * CDIM + idx];
  __syncthreads();
  const float4* wrow = (const float4*)(Wq + (size_t)m * CDIM);
  float acc0 = 0.f, acc1 = 0.f, acc2 = 0.f, acc3 = 0.f;
#pragma unroll
  for (int kq = 0; kq < CDIM / 4; ++kq) {
    float4 w = wrow[kq];
    float4 a = *(const float4*)&sH[0][kq * 4];
    float4 b = *(const float4*)&sH[1][kq * 4];
    float4 c = *(const float4*)&sH[2][kq * 4];
    float4 e = *(const float4*)&sH[3][kq * 4];
    acc0 += w.x * a.x + w.y * a.y + w.z * a.z + w.w * a.w;
    acc1 += w.x * b.x + w.y * b.y + w.z * b.z + w.w * b.w;
    acc2 += w.x * c.x + w.y * c.y + w.z * c.z + w.w * c.w;
    acc3 += w.x * e.x + w.y * e.y + w.z * e.z + w.w * e.w;
  }
  const float bias = bq[m];
  query[(size_t)(b0 + 0) * MDIM + m] = __float2bfloat16(acc0 + bias);
  query[(size_t)(b0 + 1) * MDIM + m] = __float2bfloat16(acc1 + bias);
  query[(size_t)(b0 + 2) * MDIM + m] = __float2bfloat16(acc2 + bias);
  query[(size_t)(b0 + 3) * MDIM + m] = __float2bfloat16(acc3 + bias);
}

// ---------------------------------------------------------------------------
// K3: subtree walker, v13 — v12 + d6 LDS transpose buffer.
// d6 (67MB) was stored as 64B partial-line segments at 16KB stride -> L2
// sector RMW + scattered HBM pages. Now buffered per-wave [32 b][64 keys]
// (stride 68) and flushed once per subtree as 8 instrs x 4 rows x 256B
// full-line runs — same mechanism as the d7 buffer. d5..d1 stay direct.
// ---------------------------------------------------------------------------
#define D7STR 68   // padded row stride (floats)

struct Frag { bf16x8 f[4]; };

__device__ __forceinline__ void load_frags(const bf16x8* __restrict__ kF,
                                           int blk, Frag& fr, int lane) {
#pragma unroll
  for (int kf = 0; kf < 4; ++kf)
    fr.f[kf] = kF[(size_t)(blk * 4 + kf) * 64 + lane];
}

__device__ __forceinline__ float gather_par(const f32x4 cp, int u, int lane) {
  const int src = u * 16 + (lane & 15);
  const float g0 = __shfl(cp[0], src, 64);
  const float g1 = __shfl(cp[1], src, 64);
  const float g2 = __shfl(cp[2], src, 64);
  const float g3 = __shfl(cp[3], src, 64);
  const int hi = lane >> 4;
  const float p01 = (hi & 1) ? g1 : g0;
  const float p23 = (hi & 1) ? g3 : g2;
  return (hi & 2) ? p23 : p01;
}

__device__ __forceinline__ void tile_step(
    const bf16x8* __restrict__ kF, const Frag& cur, int nextBlk, Frag& nxt,
    const bf16x8 (&qf)[2][4], const f32x4* cumPrev, int u, f32x4 (&cumOut)[2],
    float* __restrict__ oPtr, size_t span, bool doStore, bool d1mask,
    float* __restrict__ ldsDst, int lane) {
  const int c = lane & 15, hi = lane >> 4;

  // prefetch next tile's frags (L2 latency hides under this tile's compute)
  if (nextBlk >= 0) load_frags(kF, nextBlk, nxt, lane);

#pragma unroll
  for (int bt = 0; bt < 2; ++bt) {
    f32x4 acc = {};
    acc = __builtin_amdgcn_mfma_f32_16x16x32_bf16(cur.f[0], qf[bt][0], acc, 0, 0, 0);
    acc = __builtin_amdgcn_mfma_f32_16x16x32_bf16(cur.f[1], qf[bt][1], acc, 0, 0, 0);
    acc = __builtin_amdgcn_mfma_f32_16x16x32_bf16(cur.f[2], qf[bt][2], acc, 0, 0, 0);
    acc = __builtin_amdgcn_mfma_f32_16x16x32_bf16(cur.f[3], qf[bt][3], acc, 0, 0, 0);

    // group-of-4 log-softmax without max-subtraction (scores bounded)
    const float lse = __logf(__expf(acc[0]) + __expf(acc[1]) +
                             __expf(acc[2]) + __expf(acc[3]));
    float par = 0.f;
    if (cumPrev) par = gather_par(cumPrev[bt], u, lane);
    f32x4 cm;
    cm[0] = acc[0] - lse + par;
    cm[1] = acc[1] - lse + par;
    cm[2] = acc[2] - lse + par;
    cm[3] = acc[3] - lse + par;
    cumOut[bt] = cm;

    if (ldsDst) {
      *reinterpret_cast<f32x4*>(ldsDst + (bt * 16 + c) * D7STR) = cm;
    } else if (doStore && (!d1mask || hi == 0)) {
      float4 o;
      o.x = cm[0]; o.y = cm[1]; o.z = cm[2]; o.w = cm[3];
      *reinterpret_cast<float4*>(oPtr + (size_t)(bt * 16 + c) * span + hi * 4) = o;
    }
  }
}

__global__ __launch_bounds__(256) void k_tree(const bf16x8* __restrict__ kF,
                                              const __hip_bfloat16* __restrict__ query,
                                              float* __restrict__ out, int B) {
  __shared__ __align__(16) float sD7[4][32 * D7STR]; // per-wave d6-group buffer
  __shared__ __align__(16) float sD6[4][32 * D7STR]; // per-wave d6 subtree buffer

  const int tid  = threadIdx.x;
  const int lane = tid & 63;
  const int w    = tid >> 6;
  const int c    = lane & 15, hi = lane >> 4;

  const int S5  = blockIdx.x & 63;        // depth-5 subtree (XCD = S5%8)
  const int bg  = blockIdx.x >> 6;        // batch group (128 b per block)
  const int T4  = S5 >> 2;
  const int T3  = S5 >> 4;
  const int b0w = bg * 128 + w * 32;      // wave's 32-b base

  float* d7w = &sD7[w][0];
  float* d6w = &sD6[w][0];

  // query B-frags for both b-tiles (held in regs for all tiles)
  bf16x8 qf[2][4];
#pragma unroll
  for (int bt = 0; bt < 2; ++bt) {
    const __hip_bfloat16* qrow = query + (size_t)(b0w + bt * 16 + c) * MDIM;
#pragma unroll
    for (int kf = 0; kf < 4; ++kf)
      qf[bt][kf] = *reinterpret_cast<const bf16x8*>(qrow + kf * 32 + hi * 8);
  }

  Frag fA, fB;
  load_frags(kF, 0, fA, lane);            // d1 tile

  f32x4 c1[2], c2[2], c3[2], c4[2], c5[2], c6[2], c7[2];

  // d1 (blk 0): next d2 (blk 1)
  tile_step(kF, fA, 1, fB, qf, nullptr, 0, c1,
            out + (size_t)b0w * 4, 4, S5 == 0, true, nullptr, lane);
  // d2: next d3
  tile_step(kF, fB, 2 + T3, fA, qf, c1, 0, c2,
            out + (size_t)4 * B + (size_t)b0w * 16, 16, S5 == 0, false,
            nullptr, lane);
  // d3: next d4
  tile_step(kF, fA, 6 + T4, fB, qf, c2, T3, c3,
            out + (size_t)20 * B + (size_t)b0w * 64 + 16 * T3, 64,
            (S5 & 15) == 0, false, nullptr, lane);
  // d4: next d5
  tile_step(kF, fB, 22 + S5, fA, qf, c3, T4 & 3, c4,
            out + (size_t)84 * B + (size_t)b0w * 256 + 16 * T4, 256,
            (S5 & 3) == 0, false, nullptr, lane);
  // d5: next d6(u5=0)
  tile_step(kF, fA, 86 + 4 * S5, fB, qf, c4, S5 & 3, c5,
            out + (size_t)340 * B + (size_t)b0w * 1024 + 16 * S5, 1024,
            true, false, nullptr, lane);

  // d6/d7 groups. Each group = 5 tile_steps; frag parity flips per group.
#pragma unroll
  for (int u5p = 0; u5p < 2; ++u5p) {
#pragma unroll
    for (int half = 0; half < 2; ++half) {
      const int u5 = u5p * 2 + half;
      Frag& f0 = (half == 0) ? fB : fA;   // compile-time after unroll
      Frag& f1 = (half == 0) ? fA : fB;
      const int T6 = 4 * S5 + u5;
      const int d7b = 342 + 16 * S5 + 4 * u5;   // first d7 blk of this group
      // d6: buffered in sD6 (col u5*16), flushed after the u5 loop
      tile_step(kF, f0, d7b, f1, qf, c5, u5, c6,
                nullptr, 0, false, false, d6w + u5 * 16 + hi * 4, lane);
      // d7 u6=0..3
      tile_step(kF, f1, d7b + 1, f0, qf, c6, 0, c7,
                nullptr, 0, false, false, d7w + 0 * 16 + hi * 4, lane);
      tile_step(kF, f0, d7b + 2, f1, qf, c6, 1, c7,
                nullptr, 0, false, false, d7w + 1 * 16 + hi * 4, lane);
      tile_step(kF, f1, d7b + 3, f0, qf, c6, 2, c7,
                nullptr, 0, false, false, d7w + 2 * 16 + hi * 4, lane);
      tile_step(kF, f0, (u5 < 3) ? (86 + 4 * S5 + u5 + 1) : -1, f1, qf, c6, 3, c7,
                nullptr, 0, false, false, d7w + 3 * 16 + hi * 4, lane);
      // flush d6-group T6's d7: 32 b-rows; 8 instrs x 4 rows x 256B runs
      {
        float* dst = out + (size_t)5460 * B + (size_t)b0w * 16384 + 64 * T6;
#pragma unroll
        for (int j = 0; j < 8; ++j) {
          const int r = j * 4 + hi;
          f32x4 v = *reinterpret_cast<const f32x4*>(d7w + r * D7STR + c * 4);
          float4 o;
          o.x = v[0]; o.y = v[1]; o.z = v[2]; o.w = v[3];
          *reinterpret_cast<float4*>(dst + (size_t)r * 16384 + c * 4) = o;
        }
      }
    }
  }

  // flush d6 for the whole subtree: 32 b-rows x 64 keys; 8 instrs x 256B runs
  {
    float* dst = out + (size_t)1364 * B + (size_t)b0w * 4096 + 64 * S5;
#pragma unroll
    for (int j = 0; j < 8; ++j) {
      const int r = j * 4 + hi;
      f32x4 v = *reinterpret_cast<const f32x4*>(d6w + r * D7STR + c * 4);
      float4 o;
      o.x = v[0]; o.y = v[1]; o.z = v[2]; o.w = v[3];
      *reinterpret_cast<float4*>(dst + (size_t)r * 4096 + c * 4) = o;
    }
  }
}

// ---------------------------------------------------------------------------
extern "C" void kernel_launch(void* const* d_in, const int* in_sizes, int n_in,
                              void* d_out, int out_size, void* d_ws, size_t ws_size,
                              hipStream_t stream) {
  const float* hidden = (const float*)d_in[0];
  const float* Wq     = (const float*)d_in[1];
  const float* bq     = (const float*)d_in[2];
  const float* states = (const float*)d_in[3];
  const float* Wk     = (const float*)d_in[4];
  const float* bk     = (const float*)d_in[5];
  float* out = (float*)d_out;
  const int B = in_sizes[0] / CDIM;  // 4096

  __hip_bfloat16* base  = (__hip_bfloat16*)d_ws;
  bf16x8* keysF = (bf16x8*)base;                              // 5.6MB frag-ordered
  __hip_bfloat16* query = base + (size_t)NTILES * 4 * 64 * 8; // B*128 bf16
  __hip_bfloat16* wkb   = query + (size_t)B * MDIM;           // 7*128*128 bf16

  k_cvtw<<<(7 * MDIM * MDIM) / (256 * 4), 256, 0, stream>>>(Wk, wkb);
  k_query<<<B / 4, 128, 0, stream>>>(hidden, Wq, bq, query);
  k_keys_mfma<<<NTILES, 64, 0, stream>>>(states, wkb, bk, keysF);

  // grid: subtree-fastest (XCD pinning): 64 subtrees x B/128 batch groups
  k_tree<<<(B / 128) * 64, 256, 0, stream>>>(keysF, query, out, B);
}